// Round 15
// baseline (198.076 us; speedup 1.0000x reference)
//
#include <hip/hip_runtime.h>
#include <cstdint>

// MultiheadRCDA: N=8, L=300, HH=WW=96, E=256, NH=8, HD=32
// Round 15: attn v3 — dedup V reads (r12-r14 proved attn is issue-bound on
// 5x-redundant vvT reads: 184MB at ~3.7TB/s = 50us). Blocks = (bn, h/8);
// each owns ALL 300 l so its h-slice of V is read once chip-wide. fp32
// partials + tiny reduce kernel. vproj/scores/means/projections unchanged.

typedef __attribute__((ext_vector_type(8))) short short8v;  // bf16x8 MFMA frag
typedef __attribute__((ext_vector_type(4))) short short4v;  // 8B packed bf16
typedef __attribute__((ext_vector_type(4))) float f32x4;

#define SCALE_Q 0.17677669529663687f  // 32^-0.5

#define GLL16(gp, lp)                                                   \
  __builtin_amdgcn_global_load_lds(                                     \
      (const __attribute__((address_space(1))) void*)(gp),              \
      (__attribute__((address_space(3))) void*)(lp), 16, 0, 0)

__device__ __forceinline__ unsigned short f2bf(float x) {
  unsigned int u = __builtin_bit_cast(unsigned int, x);
  u += 0x7FFFu + ((u >> 16) & 1u);
  return (unsigned short)(u >> 16);
}

__device__ __forceinline__ unsigned int cvtpk(float a, float b) {
  unsigned int r;
  asm("v_cvt_pk_bf16_f32 %0, %1, %2" : "=v"(r) : "v"(a), "v"(b));
  return r;
}

__device__ __forceinline__ short8v pack8cvt(const f32x4& lo, const f32x4& hi) {
  union { short8v s; unsigned int u[4]; } z;
  z.u[0] = cvtpk(lo[0], lo[1]);
  z.u[1] = cvtpk(lo[2], lo[3]);
  z.u[2] = cvtpk(hi[0], hi[1]);
  z.u[3] = cvtpk(hi[2], hi[3]);
  return z.s;
}

__device__ __forceinline__ short4v pack4cvt(float a, float b, float c, float d) {
  union { short4v s; unsigned int u[2]; } z;
  z.u[0] = cvtpk(a, b);
  z.u[1] = cvtpk(c, d);
  return z.s;
}

__device__ __forceinline__ short8v pack8(const float4& fa, const float4& fb) {
  short8v v;
  v[0] = (short)f2bf(fa.x); v[1] = (short)f2bf(fa.y);
  v[2] = (short)f2bf(fa.z); v[3] = (short)f2bf(fa.w);
  v[4] = (short)f2bf(fb.x); v[5] = (short)f2bf(fb.y);
  v[6] = (short)f2bf(fb.z); v[7] = (short)f2bf(fb.w);
  return v;
}

// ---------------- weight fp32->bf16 ----------------
__global__ __launch_bounds__(256) void cvt_w_kernel(const float* __restrict__ w_in,
                                                    const float* __restrict__ w_out,
                                                    short* __restrict__ Wb) {
  int idx = blockIdx.x * 256 + threadIdx.x;  // 393216 total
  float v = (idx < 327680) ? w_in[idx] : w_out[idx - 327680];
  Wb[idx] = (short)f2bf(v);
}

// ---------------- mean kernels v3 ----------------
__global__ __launch_bounds__(256) void mean_over_h_v3(const float* __restrict__ in,
                                                      float* __restrict__ out) {
  __shared__ float4 part[256];
  int bw = blockIdx.x;  // b*96 + w
  int b = bw / 96, w = bw - b * 96;
  int t = threadIdx.x, e4 = t & 63, hq = t >> 6;
  const float4* p = (const float4*)(in + ((size_t)b * 9216 + w) * 256) + e4 +
                    (size_t)hq * 24 * 6144;
  float4 s = {0.f, 0.f, 0.f, 0.f};
#pragma unroll
  for (int i = 0; i < 24; ++i) {
    float4 v = p[(size_t)i * 6144];
    s.x += v.x; s.y += v.y; s.z += v.z; s.w += v.w;
  }
  part[t] = s;
  __syncthreads();
  if (t < 64) {
    float4 a = part[t], c = part[t + 64], d = part[t + 128], e = part[t + 192];
    float4 o;
    o.x = (a.x + c.x + d.x + e.x) * (1.f / 96.f);
    o.y = (a.y + c.y + d.y + e.y) * (1.f / 96.f);
    o.z = (a.z + c.z + d.z + e.z) * (1.f / 96.f);
    o.w = (a.w + c.w + d.w + e.w) * (1.f / 96.f);
    ((float4*)out)[(size_t)bw * 64 + t] = o;
  }
}

__global__ __launch_bounds__(256) void mean_over_w_v3(const float* __restrict__ in,
                                                      float* __restrict__ out) {
  __shared__ float4 part[256];
  int bh = blockIdx.x;  // b*96 + h
  int t = threadIdx.x, e4 = t & 63, wq = t >> 6;
  const float4* p = (const float4*)(in + (size_t)bh * 24576) + e4 + (size_t)wq * 24 * 64;
  float4 s = {0.f, 0.f, 0.f, 0.f};
#pragma unroll
  for (int i = 0; i < 24; ++i) {
    float4 v = p[(size_t)i * 64];
    s.x += v.x; s.y += v.y; s.z += v.z; s.w += v.w;
  }
  part[t] = s;
  __syncthreads();
  if (t < 64) {
    float4 a = part[t], c = part[t + 64], d = part[t + 128], e = part[t + 192];
    float4 o;
    o.x = (a.x + c.x + d.x + e.x) * (1.f / 96.f);
    o.y = (a.y + c.y + d.y + e.y) * (1.f / 96.f);
    o.z = (a.z + c.z + d.z + e.z) * (1.f / 96.f);
    o.w = (a.w + c.w + d.w + e.w) * (1.f / 96.f);
    ((float4*)out)[(size_t)bh * 64 + t] = o;
  }
}

// ---------------- bf16 MFMA projection GEMM (q/k/out), BM=32 ----------------
__global__ __launch_bounds__(256) void gemm_proj(
    const float* __restrict__ A0, const float* __restrict__ A1,
    const short* __restrict__ Wb, const float* __restrict__ bias,
    float* __restrict__ Cf, short* __restrict__ Cb0, short* __restrict__ Cb1,
    float scale, int mode) {
  __shared__ short As[32 * 264];
  int y = blockIdx.y;
  const float* A = y ? A1 : A0;
  short* Cb = y ? Cb1 : Cb0;
  const short* Wp = Wb + y * 65536;
  const float* bp = bias + y * 256;
  int t = threadIdx.x;
  int m0 = blockIdx.x * 32;
  int wave = t >> 6, lane = t & 63, r = lane & 15, g = lane >> 4;

  {
    int row = t >> 3, c0 = (t & 7) * 32;
    const float* ap = A + ((size_t)m0 + row) * 256 + c0;
    float4 ld[8];
#pragma unroll
    for (int j = 0; j < 8; ++j) ld[j] = *(const float4*)(ap + j * 4);
    short* dst = &As[row * 264 + c0];
#pragma unroll
    for (int j = 0; j < 4; ++j)
      *(short8v*)(dst + j * 8) = pack8(ld[2 * j], ld[2 * j + 1]);
  }
  __syncthreads();

  f32x4 acc[2][4] = {};
  const short* wbase = Wp + (size_t)(wave * 64 + r) * 256;
#pragma unroll
  for (int ks = 0; ks < 8; ++ks) {
    short8v af0 = *(const short8v*)&As[r * 264 + ks * 32 + g * 8];
    short8v af1 = *(const short8v*)&As[(16 + r) * 264 + ks * 32 + g * 8];
    short8v bf[4];
#pragma unroll
    for (int nf = 0; nf < 4; ++nf)
      bf[nf] = *(const short8v*)(wbase + nf * 16 * 256 + ks * 32 + g * 8);
#pragma unroll
    for (int nf = 0; nf < 4; ++nf) {
      acc[0][nf] = __builtin_amdgcn_mfma_f32_16x16x32_bf16(af0, bf[nf], acc[0][nf], 0, 0, 0);
      acc[1][nf] = __builtin_amdgcn_mfma_f32_16x16x32_bf16(af1, bf[nf], acc[1][nf], 0, 0, 0);
    }
  }

#pragma unroll
  for (int mf = 0; mf < 2; ++mf)
#pragma unroll
    for (int nf = 0; nf < 4; ++nf) {
      int nn = wave * 64 + nf * 16 + r;
      float bval = bp[nn];
#pragma unroll
      for (int i = 0; i < 4; ++i) {
        int m = m0 + mf * 16 + g * 4 + i;
        float val = (acc[mf][nf][i] + bval) * scale;
        if (mode == 1) {
          int bb = m / 300, ll = m - bb * 300;
          Cf[((size_t)ll * 8 + bb) * 256 + nn] = val;
        } else {  // mode 3
          Cb[(size_t)m * 256 + nn] = (short)f2bf(val);
        }
      }
    }
}

// ---------------- value projection v11 (unchanged from r14) ----------------
__global__ __launch_bounds__(512, 4) void vproj_kernel(
    const float* __restrict__ A, const short* __restrict__ Wb,
    const float* __restrict__ bias, short* __restrict__ vvT) {
  __shared__ float buf[2][16 * 260];
  __shared__ short Ts[8][32 * 36];
  int t = threadIdx.x;
  int wave = t >> 6, lane = t & 63, r = lane & 15, g = lane >> 4;
  int m0g = blockIdx.x * 144;
  int b_ = blockIdx.x >> 6;
  int hw00 = (blockIdx.x & 63) * 144;
  int chbase = wave * 32;

  short8v bf[8][2];
  {
    const short* wbase = Wb + (size_t)(chbase + r) * 256;
#pragma unroll
    for (int ks = 0; ks < 8; ++ks)
#pragma unroll
      for (int nf = 0; nf < 2; ++nf)
        bf[ks][nf] = *(const short8v*)(wbase + nf * 16 * 256 + ks * 32 + g * 8);
  }
#pragma unroll
  for (int ks = 0; ks < 8; ++ks)
#pragma unroll
    for (int nf = 0; nf < 2; ++nf)
      asm volatile("" : "+a"(bf[ks][nf]));
  float bias_v[2];
#pragma unroll
  for (int nf = 0; nf < 2; ++nf) bias_v[nf] = bias[chbase + nf * 16 + r];

#pragma unroll
  for (int q = 0; q < 2; ++q) {
#pragma unroll
    for (int i = 0; i < 2; ++i) {
      int row = wave * 2 + i;
      const float* gp = A + ((size_t)m0g + q * 16 + row) * 256 + lane * 4;
      GLL16(gp, &buf[q][row * 260]);
    }
  }

  int chg = chbase + (lane & 31);
  int half = lane >> 5;
  short* vbase = vvT + (size_t)(b_ * 8 + (chg >> 5)) * 294912 +
                 (size_t)(chg & 31) * 9216 + hw00;
  const short* tsr = &Ts[wave][(lane & 31) * 36];

#pragma unroll
  for (int tt = 0; tt < 9; ++tt) {
    if (tt == 0 || (tt & 1) || tt == 8)
      asm volatile("s_waitcnt vmcnt(2)" ::: "memory");
    else
      asm volatile("s_waitcnt vmcnt(4)" ::: "memory");
    __builtin_amdgcn_s_barrier();

    f32x4 acc[2] = {};
    const float* bp_ = &buf[tt & 1][0];
#pragma unroll
    for (int ks = 0; ks < 8; ++ks) {
      const float* p = bp_ + r * 260 + ks * 32 + g * 8;
      f32x4 lo = *(const f32x4*)p;
      f32x4 hi = *(const f32x4*)(p + 4);
      short8v af = pack8cvt(lo, hi);
      acc[0] = __builtin_amdgcn_mfma_f32_16x16x32_bf16(af, bf[ks][0], acc[0], 0, 0, 0);
      acc[1] = __builtin_amdgcn_mfma_f32_16x16x32_bf16(af, bf[ks][1], acc[1], 0, 0, 0);
    }

#pragma unroll
    for (int nf = 0; nf < 2; ++nf) {
      float bv = bias_v[nf];
      *(short4v*)&Ts[wave][(nf * 16 + r) * 36 + (tt & 1) * 16 + g * 4] =
          pack4cvt(acc[nf][0] + bv, acc[nf][1] + bv, acc[nf][2] + bv, acc[nf][3] + bv);
    }
    asm volatile("" ::: "memory");

    if (tt & 1) {
      short* gdst = vbase + (tt - 1) * 16 + half * 16;
      const short* src = tsr + half * 16;
      *(short8v*)gdst = *(const short8v*)src;
      *(short8v*)(gdst + 8) = *(const short8v*)(src + 8);
      asm volatile("" ::: "memory");
    }

    __builtin_amdgcn_s_barrier();
    if (tt + 2 < 9) {
#pragma unroll
      for (int i = 0; i < 2; ++i) {
        int row = wave * 2 + i;
        const float* gp = A + ((size_t)m0g + (tt + 2) * 16 + row) * 256 + lane * 4;
        GLL16(gp, &buf[tt & 1][row * 260]);
      }
    }
  }
  {
    short* gdst = vbase + 128 + half * 8;
    *(short8v*)gdst = *(const short8v*)(tsr + half * 8);
  }
}

// ---------------- scores + softmax: MFMA + in-register softmax ----------------
__global__ __launch_bounds__(64) void scores_softmax_v2(
    const short* __restrict__ qrb, const short* __restrict__ qcb,
    const short* __restrict__ krb, const short* __restrict__ kcb,
    short* __restrict__ wrowB, float* __restrict__ wcolT) {
  int lchunk = blockIdx.x, bn = blockIdx.y, kind = blockIdx.z;
  int b = bn >> 3, n = bn & 7;
  int lane = threadIdx.x;
  int r = lane & 15, g = lane >> 4;
  const short* qb = kind ? qcb : qrb;
  const short* kb = kind ? kcb : krb;
  int l0 = lchunk * 80;

  short8v a[5], bfr[6];
#pragma unroll
  for (int lf = 0; lf < 5; ++lf) {
    int l = l0 + lf * 16 + r;
    if (l > 299) l = 299;
    a[lf] = *(const short8v*)(qb + ((size_t)b * 300 + l) * 256 + n * 32 + g * 8);
  }
#pragma unroll
  for (int f = 0; f < 6; ++f)
    bfr[f] = *(const short8v*)(kb + ((size_t)b * 96 + f * 16 + r) * 256 + n * 32 + g * 8);

  f32x4 c[5][6];
#pragma unroll
  for (int lf = 0; lf < 5; ++lf)
#pragma unroll
    for (int f = 0; f < 6; ++f) {
      f32x4 z = {};
      c[lf][f] = __builtin_amdgcn_mfma_f32_16x16x32_bf16(a[lf], bfr[f], z, 0, 0, 0);
    }

#pragma unroll
  for (int lf = 0; lf < 5; ++lf)
#pragma unroll
    for (int i = 0; i < 4; ++i) {
      float m = c[lf][0][i];
#pragma unroll
      for (int f = 1; f < 6; ++f) m = fmaxf(m, c[lf][f][i]);
#pragma unroll
      for (int mask = 1; mask <= 8; mask <<= 1) m = fmaxf(m, __shfl_xor(m, mask, 64));
      float e[6], s = 0.f;
#pragma unroll
      for (int f = 0; f < 6; ++f) { e[f] = __expf(c[lf][f][i] - m); s += e[f]; }
#pragma unroll
      for (int mask = 1; mask <= 8; mask <<= 1) s += __shfl_xor(s, mask, 64);
      float inv = 1.f / s;
#pragma unroll
      for (int f = 0; f < 6; ++f) c[lf][f][i] = e[f] * inv;
    }

  if (kind == 0) {
#pragma unroll
    for (int lf = 0; lf < 5; ++lf)
#pragma unroll
      for (int i = 0; i < 4; ++i) {
        int l = l0 + lf * 16 + g * 4 + i;
        bool ok = (l < 300);
#pragma unroll
        for (int f = 0; f < 6; ++f) {
          float wv = ok ? c[lf][f][i] : 0.f;
          wrowB[((size_t)bn * 320 + l) * 96 + f * 16 + r] = (short)f2bf(wv);
        }
      }
  } else {
#pragma unroll
    for (int lf = 0; lf < 5; ++lf)
#pragma unroll
      for (int f = 0; f < 6; ++f) {
        int l = l0 + lf * 16 + g * 4;
        f32x4 wv = c[lf][f];
#pragma unroll
        for (int i = 0; i < 4; ++i) if (l + i >= 300) wv[i] = 0.f;
        *(f32x4*)(wcolT + ((size_t)bn * 96 + f * 16 + r) * 320 + l) = wv;
      }
  }
}

// ---------------- attention v3: block = (bn, h/8), owns all 300 l ----------
// part[hq][bn][320][32] fp32 partials; vvT h-slices are disjoint -> V read
// once chip-wide. 8 waves = 2 df x 4 lq (80 l each). Same-bn blocks share XCD.
__global__ __launch_bounds__(512, 2) void attn_v3(
    const short* __restrict__ wrowB, const float* __restrict__ wcolT,
    const short* __restrict__ vvT, float* __restrict__ part) {
  int i = blockIdx.x;
  int xcd = i & 7, j = i >> 3;          // j 0..63
  int bn = ((j & 7) << 3) + xcd;        // all 8 hq-blocks of a bn -> same XCD
  int hq = j >> 3;                      // 0..7, 12 h each
  int t = threadIdx.x, wave = t >> 6, lane = t & 63;
  int df = wave & 1, lq = wave >> 1;    // lq 0..3 -> l-chunk of 80
  int l0 = lq * 80;
  int r = lane & 15, g = lane >> 4;

  // wr A-frags for this wave's 80 l, loaded once (60 VGPR)
  short8v a[5][3];
  const short* wr = wrowB + (size_t)bn * 320 * 96;
#pragma unroll
  for (int lf = 0; lf < 5; ++lf)
#pragma unroll
    for (int ks = 0; ks < 3; ++ks)
      a[lf][ks] = *(const short8v*)(wr + (l0 + lf * 16 + r) * 96 + ks * 32 + g * 8);

  const short* vb = vvT + (size_t)bn * 294912 + (size_t)(df * 16 + r) * 9216 +
                    hq * 12 * 96;
  const float* wcb = wcolT + ((size_t)bn * 96 + hq * 12) * 320 + l0 + g * 4;

  f32x4 acc[5] = {};
  short8v bR[2][3];
  f32x4 wR[2][5];
#pragma unroll
  for (int ks = 0; ks < 3; ++ks) bR[0][ks] = *(const short8v*)(vb + ks * 32 + g * 8);
#pragma unroll
  for (int lf = 0; lf < 5; ++lf) wR[0][lf] = *(const f32x4*)(wcb + lf * 16);
  asm volatile("" ::: "memory");

#pragma unroll
  for (int hs = 0; hs < 12; ++hs) {
    int cur = hs & 1, nxt = cur ^ 1;
    if (hs < 11) {  // prefetch h-step hs+1 before computing hs
#pragma unroll
      for (int ks = 0; ks < 3; ++ks)
        bR[nxt][ks] = *(const short8v*)(vb + (hs + 1) * 96 + ks * 32 + g * 8);
#pragma unroll
      for (int lf = 0; lf < 5; ++lf)
        wR[nxt][lf] = *(const f32x4*)(wcb + (hs + 1) * 320 + lf * 16);
    }
    f32x4 R[5] = {};
#pragma unroll
    for (int ks = 0; ks < 3; ++ks)
#pragma unroll
      for (int lf = 0; lf < 5; ++lf)
        R[lf] = __builtin_amdgcn_mfma_f32_16x16x32_bf16(a[lf][ks], bR[cur][ks], R[lf], 0, 0, 0);
#pragma unroll
    for (int lf = 0; lf < 5; ++lf) acc[lf] += wR[cur][lf] * R[lf];
    asm volatile("" ::: "memory");  // keep prefetch loads in this iteration
  }

  // store fp32 partial: part[((hq*64+bn)*320 + l)*32 + df*16 + r]
  float* pb = part + ((size_t)(hq * 64 + bn) * 320) * 32 + df * 16 + r;
#pragma unroll
  for (int lf = 0; lf < 5; ++lf)
#pragma unroll
    for (int i2 = 0; i2 < 4; ++i2) {
      int l = l0 + lf * 16 + g * 4 + i2;
      pb[(size_t)l * 32] = acc[lf][i2];
      pb += 0;  // no-op
    }
  // note: the l index varies per store; recompute address explicitly:
}

// (clean version of the partial store is inside attn_v3 above via pb[l*32])

// ---------------- reduce 8 partials -> ao ----------------
__global__ __launch_bounds__(256) void reduce_kernel(const float* __restrict__ part,
                                                     float* __restrict__ ao) {
  int idx = blockIdx.x * 256 + threadIdx.x;  // 64*300*32 = 614400
  int d = idx & 31;
  int rest = idx >> 5;
  int l = rest % 300;
  int bn = rest / 300;
  float s = 0.f;
#pragma unroll
  for (int hq = 0; hq < 8; ++hq)
    s += part[((size_t)(hq * 64 + bn) * 320 + l) * 32 + d];
  int b = bn >> 3, n = bn & 7;
  ao[((size_t)b * 300 + l) * 256 + n * 32 + d] = s;
}

// ---------------- launch ----------------
extern "C" void kernel_launch(void* const* d_in, const int* in_sizes, int n_in,
                              void* d_out, int out_size, void* d_ws, size_t ws_size,
                              hipStream_t stream) {
  const float* query_row = (const float*)d_in[0];
  const float* query_col = (const float*)d_in[1];
  const float* key_row   = (const float*)d_in[2];
  const float* key_col   = (const float*)d_in[3];
  const float* value     = (const float*)d_in[4];
  const float* W         = (const float*)d_in[5];  // (1280,256)
  const float* Bv        = (const float*)d_in[6];  // (1280,)
  const float* Wout      = (const float*)d_in[7];  // (256,256)
  const float* Bout      = (const float*)d_in[8];  // (256,)

  float* ws = (float*)d_ws;
  float* krm   = ws;                        // 196608 f
  float* kcm   = krm + 196608;              // 196608 f
  float* ao    = kcm + 196608;              // 614400 f
  float* wcolT = ao + 614400;               // 1966080 f
  float* part  = wcolT + 1966080;           // 8*64*320*32 = 5242880 f
  short* qrb   = (short*)(part + 5242880);  // 614400 s
  short* qcb   = qrb + 614400;              // 614400 s
  short* krb   = qcb + 614400;              // 196608 s
  short* kcb   = krb + 196608;              // 196608 s
  short* wrowB = kcb + 196608;              // 1966080 s
  short* vvT   = wrowB + 1966080;           // 18874368 s
  short* Wb    = vvT + 18874368;            // 393216 s
  // total ~78.6 MB

  cvt_w_kernel<<<1536, 256, 0, stream>>>(W, Wout, Wb);
  mean_over_h_v3<<<768, 256, 0, stream>>>(key_row, krm);
  mean_over_w_v3<<<768, 256, 0, stream>>>(key_col, kcm);
  gemm_proj<<<dim3(75, 2), 256, 0, stream>>>(query_row, query_col, Wb, Bv,
                                             nullptr, qrb, qcb, SCALE_Q, 3);
  gemm_proj<<<dim3(24, 2), 256, 0, stream>>>(krm, kcm, Wb + 131072, Bv + 512,
                                             nullptr, krb, kcb, 1.f, 3);
  vproj_kernel<<<512, 512, 0, stream>>>(value, Wb + 262144, Bv + 1024, vvT);
  scores_softmax_v2<<<dim3(4, 64, 2), 64, 0, stream>>>(qrb, qcb, krb, kcb, wrowB, wcolT);
  attn_v3<<<512, 512, 0, stream>>>(wrowB, wcolT, vvT, part);
  reduce_kernel<<<2400, 256, 0, stream>>>(part, ao);
  gemm_proj<<<dim3(75, 1), 256, 0, stream>>>(ao, nullptr, Wb + 327680, Bout,
                                             (float*)d_out, nullptr, nullptr, 1.f, 1);
}

// Round 16
// 157.674 us; speedup vs baseline: 1.2562x; 1.2562x over previous
//
#include <hip/hip_runtime.h>
#include <cstdint>

// MultiheadRCDA: N=8, L=300, HH=WW=96, E=256, NH=8, HD=32
// Round 16: revert attn to r12 structure (attn_v3's partial stores caused 9x
// write amplification); split h into 2 block-halves (12-step chains, 640
// blocks, part0/part1 summed inside out-proj). vproj: 96-row blocks, grid
// 768 = exactly 3 blocks/CU.

typedef __attribute__((ext_vector_type(8))) short short8v;  // bf16x8 MFMA frag
typedef __attribute__((ext_vector_type(4))) short short4v;  // 8B packed bf16
typedef __attribute__((ext_vector_type(4))) float f32x4;

#define SCALE_Q 0.17677669529663687f  // 32^-0.5

#define GLL16(gp, lp)                                                   \
  __builtin_amdgcn_global_load_lds(                                     \
      (const __attribute__((address_space(1))) void*)(gp),              \
      (__attribute__((address_space(3))) void*)(lp), 16, 0, 0)

__device__ __forceinline__ unsigned short f2bf(float x) {
  unsigned int u = __builtin_bit_cast(unsigned int, x);
  u += 0x7FFFu + ((u >> 16) & 1u);
  return (unsigned short)(u >> 16);
}

__device__ __forceinline__ unsigned int cvtpk(float a, float b) {
  unsigned int r;
  asm("v_cvt_pk_bf16_f32 %0, %1, %2" : "=v"(r) : "v"(a), "v"(b));
  return r;
}

__device__ __forceinline__ short8v pack8cvt(const f32x4& lo, const f32x4& hi) {
  union { short8v s; unsigned int u[4]; } z;
  z.u[0] = cvtpk(lo[0], lo[1]);
  z.u[1] = cvtpk(lo[2], lo[3]);
  z.u[2] = cvtpk(hi[0], hi[1]);
  z.u[3] = cvtpk(hi[2], hi[3]);
  return z.s;
}

__device__ __forceinline__ short4v pack4cvt(float a, float b, float c, float d) {
  union { short4v s; unsigned int u[2]; } z;
  z.u[0] = cvtpk(a, b);
  z.u[1] = cvtpk(c, d);
  return z.s;
}

__device__ __forceinline__ short8v pack8(const float4& fa, const float4& fb) {
  short8v v;
  v[0] = (short)f2bf(fa.x); v[1] = (short)f2bf(fa.y);
  v[2] = (short)f2bf(fa.z); v[3] = (short)f2bf(fa.w);
  v[4] = (short)f2bf(fb.x); v[5] = (short)f2bf(fb.y);
  v[6] = (short)f2bf(fb.z); v[7] = (short)f2bf(fb.w);
  return v;
}

// ---------------- weight fp32->bf16 ----------------
__global__ __launch_bounds__(256) void cvt_w_kernel(const float* __restrict__ w_in,
                                                    const float* __restrict__ w_out,
                                                    short* __restrict__ Wb) {
  int idx = blockIdx.x * 256 + threadIdx.x;  // 393216 total
  float v = (idx < 327680) ? w_in[idx] : w_out[idx - 327680];
  Wb[idx] = (short)f2bf(v);
}

// ---------------- mean kernels v3 ----------------
__global__ __launch_bounds__(256) void mean_over_h_v3(const float* __restrict__ in,
                                                      float* __restrict__ out) {
  __shared__ float4 part[256];
  int bw = blockIdx.x;  // b*96 + w
  int b = bw / 96, w = bw - b * 96;
  int t = threadIdx.x, e4 = t & 63, hq = t >> 6;
  const float4* p = (const float4*)(in + ((size_t)b * 9216 + w) * 256) + e4 +
                    (size_t)hq * 24 * 6144;
  float4 s = {0.f, 0.f, 0.f, 0.f};
#pragma unroll
  for (int i = 0; i < 24; ++i) {
    float4 v = p[(size_t)i * 6144];
    s.x += v.x; s.y += v.y; s.z += v.z; s.w += v.w;
  }
  part[t] = s;
  __syncthreads();
  if (t < 64) {
    float4 a = part[t], c = part[t + 64], d = part[t + 128], e = part[t + 192];
    float4 o;
    o.x = (a.x + c.x + d.x + e.x) * (1.f / 96.f);
    o.y = (a.y + c.y + d.y + e.y) * (1.f / 96.f);
    o.z = (a.z + c.z + d.z + e.z) * (1.f / 96.f);
    o.w = (a.w + c.w + d.w + e.w) * (1.f / 96.f);
    ((float4*)out)[(size_t)bw * 64 + t] = o;
  }
}

__global__ __launch_bounds__(256) void mean_over_w_v3(const float* __restrict__ in,
                                                      float* __restrict__ out) {
  __shared__ float4 part[256];
  int bh = blockIdx.x;  // b*96 + h
  int t = threadIdx.x, e4 = t & 63, wq = t >> 6;
  const float4* p = (const float4*)(in + (size_t)bh * 24576) + e4 + (size_t)wq * 24 * 64;
  float4 s = {0.f, 0.f, 0.f, 0.f};
#pragma unroll
  for (int i = 0; i < 24; ++i) {
    float4 v = p[(size_t)i * 64];
    s.x += v.x; s.y += v.y; s.z += v.z; s.w += v.w;
  }
  part[t] = s;
  __syncthreads();
  if (t < 64) {
    float4 a = part[t], c = part[t + 64], d = part[t + 128], e = part[t + 192];
    float4 o;
    o.x = (a.x + c.x + d.x + e.x) * (1.f / 96.f);
    o.y = (a.y + c.y + d.y + e.y) * (1.f / 96.f);
    o.z = (a.z + c.z + d.z + e.z) * (1.f / 96.f);
    o.w = (a.w + c.w + d.w + e.w) * (1.f / 96.f);
    ((float4*)out)[(size_t)bh * 64 + t] = o;
  }
}

// ---------------- bf16 MFMA projection GEMM (q/k/out), BM=32 ----------------
// Aadd: optional second fp32 source summed into A at stage time (h-half merge).
__global__ __launch_bounds__(256) void gemm_proj(
    const float* __restrict__ A0, const float* __restrict__ A1,
    const float* __restrict__ Aadd,
    const short* __restrict__ Wb, const float* __restrict__ bias,
    float* __restrict__ Cf, short* __restrict__ Cb0, short* __restrict__ Cb1,
    float scale, int mode) {
  __shared__ short As[32 * 264];
  int y = blockIdx.y;
  const float* A = y ? A1 : A0;
  short* Cb = y ? Cb1 : Cb0;
  const short* Wp = Wb + y * 65536;
  const float* bp = bias + y * 256;
  int t = threadIdx.x;
  int m0 = blockIdx.x * 32;
  int wave = t >> 6, lane = t & 63, r = lane & 15, g = lane >> 4;

  {
    int row = t >> 3, c0 = (t & 7) * 32;
    size_t off = ((size_t)m0 + row) * 256 + c0;
    const float* ap = A + off;
    float4 ld[8];
#pragma unroll
    for (int j = 0; j < 8; ++j) ld[j] = *(const float4*)(ap + j * 4);
    if (Aadd) {
      const float* aq = Aadd + off;
#pragma unroll
      for (int j = 0; j < 8; ++j) {
        float4 e = *(const float4*)(aq + j * 4);
        ld[j].x += e.x; ld[j].y += e.y; ld[j].z += e.z; ld[j].w += e.w;
      }
    }
    short* dst = &As[row * 264 + c0];
#pragma unroll
    for (int j = 0; j < 4; ++j)
      *(short8v*)(dst + j * 8) = pack8(ld[2 * j], ld[2 * j + 1]);
  }
  __syncthreads();

  f32x4 acc[2][4] = {};
  const short* wbase = Wp + (size_t)(wave * 64 + r) * 256;
#pragma unroll
  for (int ks = 0; ks < 8; ++ks) {
    short8v af0 = *(const short8v*)&As[r * 264 + ks * 32 + g * 8];
    short8v af1 = *(const short8v*)&As[(16 + r) * 264 + ks * 32 + g * 8];
    short8v bf[4];
#pragma unroll
    for (int nf = 0; nf < 4; ++nf)
      bf[nf] = *(const short8v*)(wbase + nf * 16 * 256 + ks * 32 + g * 8);
#pragma unroll
    for (int nf = 0; nf < 4; ++nf) {
      acc[0][nf] = __builtin_amdgcn_mfma_f32_16x16x32_bf16(af0, bf[nf], acc[0][nf], 0, 0, 0);
      acc[1][nf] = __builtin_amdgcn_mfma_f32_16x16x32_bf16(af1, bf[nf], acc[1][nf], 0, 0, 0);
    }
  }

#pragma unroll
  for (int mf = 0; mf < 2; ++mf)
#pragma unroll
    for (int nf = 0; nf < 4; ++nf) {
      int nn = wave * 64 + nf * 16 + r;
      float bval = bp[nn];
#pragma unroll
      for (int i = 0; i < 4; ++i) {
        int m = m0 + mf * 16 + g * 4 + i;
        float val = (acc[mf][nf][i] + bval) * scale;
        if (mode == 1) {
          int bb = m / 300, ll = m - bb * 300;
          Cf[((size_t)ll * 8 + bb) * 256 + nn] = val;
        } else {  // mode 3
          Cb[(size_t)m * 256 + nn] = (short)f2bf(val);
        }
      }
    }
}

// ---------------- value projection v12 (3 blocks/CU) ----------------
// vvT[bn][d(32)][hw(9216)] bf16. grid 768 x 512 thr; 96 rows/block
// (6 tiles of 16); 8 waves x 32 channels; counted vmcnt; pair stores.
__global__ __launch_bounds__(512, 4) void vproj_kernel(
    const float* __restrict__ A, const short* __restrict__ Wb,
    const float* __restrict__ bias, short* __restrict__ vvT) {
  __shared__ float buf[2][16 * 260];   // 33.3 KB
  __shared__ short Ts[8][32 * 36];     // 18.4 KB
  int t = threadIdx.x;
  int wave = t >> 6, lane = t & 63, r = lane & 15, g = lane >> 4;
  int m0g = blockIdx.x * 96;
  int b_ = blockIdx.x / 96;            // 96 blocks per batch (9216/96)
  int hw00 = (blockIdx.x - b_ * 96) * 96;
  int chbase = wave * 32;

  short8v bf[8][2];
  {
    const short* wbase = Wb + (size_t)(chbase + r) * 256;
#pragma unroll
    for (int ks = 0; ks < 8; ++ks)
#pragma unroll
      for (int nf = 0; nf < 2; ++nf)
        bf[ks][nf] = *(const short8v*)(wbase + nf * 16 * 256 + ks * 32 + g * 8);
  }
#pragma unroll
  for (int ks = 0; ks < 8; ++ks)
#pragma unroll
    for (int nf = 0; nf < 2; ++nf)
      asm volatile("" : "+a"(bf[ks][nf]));
  float bias_v[2];
#pragma unroll
  for (int nf = 0; nf < 2; ++nf) bias_v[nf] = bias[chbase + nf * 16 + r];

  // prologue: stage tiles 0,1; wave stages rows wave*2, wave*2+1
#pragma unroll
  for (int q = 0; q < 2; ++q) {
#pragma unroll
    for (int i = 0; i < 2; ++i) {
      int row = wave * 2 + i;
      const float* gp = A + ((size_t)m0g + q * 16 + row) * 256 + lane * 4;
      GLL16(gp, &buf[q][row * 260]);
    }
  }

  int chg = chbase + (lane & 31);
  int half = lane >> 5;
  short* vbase = vvT + (size_t)(b_ * 8 + (chg >> 5)) * 294912 +
                 (size_t)(chg & 31) * 9216 + hw00;
  const short* tsr = &Ts[wave][(lane & 31) * 36];

#pragma unroll
  for (int tt = 0; tt < 6; ++tt) {
    // counted wait for tile tt's 2 GLLs (derived for 6-tile schedule)
    if (tt == 5)                  asm volatile("s_waitcnt vmcnt(0)" ::: "memory");
    else if (tt == 2 || tt == 4)  asm volatile("s_waitcnt vmcnt(4)" ::: "memory");
    else                          asm volatile("s_waitcnt vmcnt(2)" ::: "memory");
    __builtin_amdgcn_s_barrier();

    f32x4 acc[2] = {};
    const float* bp_ = &buf[tt & 1][0];
#pragma unroll
    for (int ks = 0; ks < 8; ++ks) {
      const float* p = bp_ + r * 260 + ks * 32 + g * 8;
      f32x4 lo = *(const f32x4*)p;
      f32x4 hi = *(const f32x4*)(p + 4);
      short8v af = pack8cvt(lo, hi);
      acc[0] = __builtin_amdgcn_mfma_f32_16x16x32_bf16(af, bf[ks][0], acc[0], 0, 0, 0);
      acc[1] = __builtin_amdgcn_mfma_f32_16x16x32_bf16(af, bf[ks][1], acc[1], 0, 0, 0);
    }

#pragma unroll
    for (int nf = 0; nf < 2; ++nf) {
      float bv = bias_v[nf];
      *(short4v*)&Ts[wave][(nf * 16 + r) * 36 + (tt & 1) * 16 + g * 4] =
          pack4cvt(acc[nf][0] + bv, acc[nf][1] + bv, acc[nf][2] + bv, acc[nf][3] + bv);
    }
    asm volatile("" ::: "memory");

    if (tt & 1) {  // store tiles (tt-1, tt): 32 hw = 64B per channel
      short* gdst = vbase + (tt - 1) * 16 + half * 16;
      const short* src = tsr + half * 16;
      *(short8v*)gdst = *(const short8v*)src;
      *(short8v*)(gdst + 8) = *(const short8v*)(src + 8);
      asm volatile("" ::: "memory");
    }

    __builtin_amdgcn_s_barrier();
    if (tt + 2 < 6) {
#pragma unroll
      for (int i = 0; i < 2; ++i) {
        int row = wave * 2 + i;
        const float* gp = A + ((size_t)m0g + (tt + 2) * 16 + row) * 256 + lane * 4;
        GLL16(gp, &buf[tt & 1][row * 260]);
      }
    }
  }
}

// ---------------- scores + softmax: MFMA + in-register softmax ----------------
__global__ __launch_bounds__(64) void scores_softmax_v2(
    const short* __restrict__ qrb, const short* __restrict__ qcb,
    const short* __restrict__ krb, const short* __restrict__ kcb,
    short* __restrict__ wrowB, float* __restrict__ wcolT) {
  int lchunk = blockIdx.x, bn = blockIdx.y, kind = blockIdx.z;
  int b = bn >> 3, n = bn & 7;
  int lane = threadIdx.x;
  int r = lane & 15, g = lane >> 4;
  const short* qb = kind ? qcb : qrb;
  const short* kb = kind ? kcb : krb;
  int l0 = lchunk * 80;

  short8v a[5], bfr[6];
#pragma unroll
  for (int lf = 0; lf < 5; ++lf) {
    int l = l0 + lf * 16 + r;
    if (l > 299) l = 299;
    a[lf] = *(const short8v*)(qb + ((size_t)b * 300 + l) * 256 + n * 32 + g * 8);
  }
#pragma unroll
  for (int f = 0; f < 6; ++f)
    bfr[f] = *(const short8v*)(kb + ((size_t)b * 96 + f * 16 + r) * 256 + n * 32 + g * 8);

  f32x4 c[5][6];
#pragma unroll
  for (int lf = 0; lf < 5; ++lf)
#pragma unroll
    for (int f = 0; f < 6; ++f) {
      f32x4 z = {};
      c[lf][f] = __builtin_amdgcn_mfma_f32_16x16x32_bf16(a[lf], bfr[f], z, 0, 0, 0);
    }

#pragma unroll
  for (int lf = 0; lf < 5; ++lf)
#pragma unroll
    for (int i = 0; i < 4; ++i) {
      float m = c[lf][0][i];
#pragma unroll
      for (int f = 1; f < 6; ++f) m = fmaxf(m, c[lf][f][i]);
#pragma unroll
      for (int mask = 1; mask <= 8; mask <<= 1) m = fmaxf(m, __shfl_xor(m, mask, 64));
      float e[6], s = 0.f;
#pragma unroll
      for (int f = 0; f < 6; ++f) { e[f] = __expf(c[lf][f][i] - m); s += e[f]; }
#pragma unroll
      for (int mask = 1; mask <= 8; mask <<= 1) s += __shfl_xor(s, mask, 64);
      float inv = 1.f / s;
#pragma unroll
      for (int f = 0; f < 6; ++f) c[lf][f][i] = e[f] * inv;
    }

  if (kind == 0) {
#pragma unroll
    for (int lf = 0; lf < 5; ++lf)
#pragma unroll
      for (int i = 0; i < 4; ++i) {
        int l = l0 + lf * 16 + g * 4 + i;
        bool ok = (l < 300);
#pragma unroll
        for (int f = 0; f < 6; ++f) {
          float wv = ok ? c[lf][f][i] : 0.f;
          wrowB[((size_t)bn * 320 + l) * 96 + f * 16 + r] = (short)f2bf(wv);
        }
      }
  } else {
#pragma unroll
    for (int lf = 0; lf < 5; ++lf)
#pragma unroll
      for (int f = 0; f < 6; ++f) {
        int l = l0 + lf * 16 + g * 4;
        f32x4 wv = c[lf][f];
#pragma unroll
        for (int i = 0; i < 4; ++i) if (l + i >= 300) wv[i] = 0.f;
        *(f32x4*)(wcolT + ((size_t)bn * 96 + f * 16 + r) * 320 + l) = wv;
      }
  }
}

// ---------------- fused bilinear attention (r12 structure, h split x2) ----
// grid 640: (bn, lh(5), hh2(2)); 8 waves = df(2) x hq(4); 12 h-steps/wave.
// Output to part0/part1 (summed in out-proj).
__global__ __launch_bounds__(512, 2) void attn_kernel(
    const short* __restrict__ wrowB, const float* __restrict__ wcolT,
    const short* __restrict__ vvT, float* __restrict__ part0,
    float* __restrict__ part1) {
  __shared__ f32x4 cmb[3][2][4][64];
  int i = blockIdx.x;
  int xcd = i & 7, j = i >> 3;          // j 0..79
  int grp = j / 10, rem = j - grp * 10;
  int bn = grp * 8 + xcd;               // all 10 blocks of a bn -> same XCD
  int lh = rem >> 1, hh2 = rem & 1;
  int b = bn >> 3, n = bn & 7;
  int t = threadIdx.x, wave = t >> 6, lane = t & 63;
  int df = wave & 1, hq = wave >> 1;    // hq 0..3, 12 h each
  int lbase = lh * 64;
  int r = lane & 15, g = lane >> 4;
  int hbase = hh2 * 48 + hq * 12;

  short8v a[4][3];
  const short* wr = wrowB + (size_t)bn * 320 * 96;
#pragma unroll
  for (int lf = 0; lf < 4; ++lf)
#pragma unroll
    for (int ks = 0; ks < 3; ++ks)
      a[lf][ks] = *(const short8v*)(wr + (lbase + lf * 16 + r) * 96 + ks * 32 + g * 8);

  const short* vb = vvT + (size_t)bn * 294912 + (size_t)(df * 16 + r) * 9216 + hbase * 96;
  const float* wcb = wcolT + ((size_t)bn * 96 + hbase) * 320 + lbase + g * 4;

  f32x4 acc[4] = {};
  short8v b0[3], b1[3];
  f32x4 w0[4], w1[4];
#pragma unroll
  for (int ks = 0; ks < 3; ++ks) b0[ks] = *(const short8v*)(vb + ks * 32 + g * 8);
#pragma unroll
  for (int lf = 0; lf < 4; ++lf) w0[lf] = *(const f32x4*)(wcb + lf * 16);

#pragma unroll
  for (int h2 = 0; h2 < 6; ++h2) {
    int h = h2 * 2;
#pragma unroll
    for (int ks = 0; ks < 3; ++ks) b1[ks] = *(const short8v*)(vb + (h + 1) * 96 + ks * 32 + g * 8);
#pragma unroll
    for (int lf = 0; lf < 4; ++lf) w1[lf] = *(const f32x4*)(wcb + (h + 1) * 320 + lf * 16);
    {
      f32x4 R[4] = {};
#pragma unroll
      for (int ks = 0; ks < 3; ++ks)
#pragma unroll
        for (int lf = 0; lf < 4; ++lf)
          R[lf] = __builtin_amdgcn_mfma_f32_16x16x32_bf16(a[lf][ks], b0[ks], R[lf], 0, 0, 0);
#pragma unroll
      for (int lf = 0; lf < 4; ++lf) acc[lf] += w0[lf] * R[lf];
    }
    if (h2 < 5) {
#pragma unroll
      for (int ks = 0; ks < 3; ++ks) b0[ks] = *(const short8v*)(vb + (h + 2) * 96 + ks * 32 + g * 8);
#pragma unroll
      for (int lf = 0; lf < 4; ++lf) w0[lf] = *(const f32x4*)(wcb + (h + 2) * 320 + lf * 16);
    }
    {
      f32x4 R[4] = {};
#pragma unroll
      for (int ks = 0; ks < 3; ++ks)
#pragma unroll
        for (int lf = 0; lf < 4; ++lf)
          R[lf] = __builtin_amdgcn_mfma_f32_16x16x32_bf16(a[lf][ks], b1[ks], R[lf], 0, 0, 0);
#pragma unroll
      for (int lf = 0; lf < 4; ++lf) acc[lf] += w1[lf] * R[lf];
    }
  }

  if (hq > 0) {
#pragma unroll
    for (int lf = 0; lf < 4; ++lf) cmb[hq - 1][df][lf][lane] = acc[lf];
  }
  __syncthreads();
  if (hq == 0) {
    float* po = hh2 ? part1 : part0;
#pragma unroll
    for (int lf = 0; lf < 4; ++lf) {
      f32x4 o = acc[lf];
#pragma unroll
      for (int q = 0; q < 3; ++q) o += cmb[q][df][lf][lane];
#pragma unroll
      for (int i2 = 0; i2 < 4; ++i2) {
        int l = lbase + lf * 16 + g * 4 + i2;
        if (l < 300)
          po[((size_t)b * 300 + l) * 256 + n * 32 + df * 16 + r] = o[i2];
      }
    }
  }
}

// ---------------- launch ----------------
extern "C" void kernel_launch(void* const* d_in, const int* in_sizes, int n_in,
                              void* d_out, int out_size, void* d_ws, size_t ws_size,
                              hipStream_t stream) {
  const float* query_row = (const float*)d_in[0];
  const float* query_col = (const float*)d_in[1];
  const float* key_row   = (const float*)d_in[2];
  const float* key_col   = (const float*)d_in[3];
  const float* value     = (const float*)d_in[4];
  const float* W         = (const float*)d_in[5];  // (1280,256)
  const float* Bv        = (const float*)d_in[6];  // (1280,)
  const float* Wout      = (const float*)d_in[7];  // (256,256)
  const float* Bout      = (const float*)d_in[8];  // (256,)

  float* ws = (float*)d_ws;
  float* krm   = ws;                        // 196608 f
  float* kcm   = krm + 196608;              // 196608 f
  float* part0 = kcm + 196608;              // 614400 f
  float* part1 = part0 + 614400;            // 614400 f
  float* wcolT = part1 + 614400;            // 1966080 f
  short* qrb   = (short*)(wcolT + 1966080); // 614400 s
  short* qcb   = qrb + 614400;              // 614400 s
  short* krb   = qcb + 614400;              // 196608 s
  short* kcb   = krb + 196608;              // 196608 s
  short* wrowB = kcb + 196608;              // 1966080 s
  short* vvT   = wrowB + 1966080;           // 18874368 s
  short* Wb    = vvT + 18874368;            // 393216 s

  cvt_w_kernel<<<1536, 256, 0, stream>>>(W, Wout, Wb);
  mean_over_h_v3<<<768, 256, 0, stream>>>(key_row, krm);
  mean_over_w_v3<<<768, 256, 0, stream>>>(key_col, kcm);
  gemm_proj<<<dim3(75, 2), 256, 0, stream>>>(query_row, query_col, nullptr, Wb, Bv,
                                             nullptr, qrb, qcb, SCALE_Q, 3);
  gemm_proj<<<dim3(24, 2), 256, 0, stream>>>(krm, kcm, nullptr, Wb + 131072, Bv + 512,
                                             nullptr, krb, kcb, 1.f, 3);
  vproj_kernel<<<768, 512, 0, stream>>>(value, Wb + 262144, Bv + 1024, vvT);
  scores_softmax_v2<<<dim3(4, 64, 2), 64, 0, stream>>>(qrb, qcb, krb, kcb, wrowB, wcolT);
  attn_kernel<<<640, 512, 0, stream>>>(wrowB, wcolT, vvT, part0, part1);
  gemm_proj<<<dim3(75, 1), 256, 0, stream>>>(part0, nullptr, part1, Wb + 327680, Bout,
                                             (float*)d_out, nullptr, nullptr, 1.f, 1);
}

// Round 17
// 155.359 us; speedup vs baseline: 1.2750x; 1.0149x over previous
//
#include <hip/hip_runtime.h>
#include <cstdint>

// MultiheadRCDA: N=8, L=300, HH=WW=96, E=256, NH=8, HD=32
// Round 17: concurrency by fusion. mega1 = vproj + both means interleaved by
// blockIdx parity (means' 227MB HBM stream hides under vproj's latency-bound
// pipeline, which only uses 870GB/s). gemm512 = kproj+qproj in one launch.
// attn (r16 h-split) / scores / out-proj unchanged.

typedef __attribute__((ext_vector_type(8))) short short8v;  // bf16x8 MFMA frag
typedef __attribute__((ext_vector_type(4))) short short4v;  // 8B packed bf16
typedef __attribute__((ext_vector_type(4))) float f32x4;

#define SCALE_Q 0.17677669529663687f  // 32^-0.5

#define GLL16(gp, lp)                                                   \
  __builtin_amdgcn_global_load_lds(                                     \
      (const __attribute__((address_space(1))) void*)(gp),              \
      (__attribute__((address_space(3))) void*)(lp), 16, 0, 0)

__device__ __forceinline__ unsigned short f2bf(float x) {
  unsigned int u = __builtin_bit_cast(unsigned int, x);
  u += 0x7FFFu + ((u >> 16) & 1u);
  return (unsigned short)(u >> 16);
}

__device__ __forceinline__ unsigned int cvtpk(float a, float b) {
  unsigned int r;
  asm("v_cvt_pk_bf16_f32 %0, %1, %2" : "=v"(r) : "v"(a), "v"(b));
  return r;
}

__device__ __forceinline__ short8v pack8cvt(const f32x4& lo, const f32x4& hi) {
  union { short8v s; unsigned int u[4]; } z;
  z.u[0] = cvtpk(lo[0], lo[1]);
  z.u[1] = cvtpk(lo[2], lo[3]);
  z.u[2] = cvtpk(hi[0], hi[1]);
  z.u[3] = cvtpk(hi[2], hi[3]);
  return z.s;
}

__device__ __forceinline__ short4v pack4cvt(float a, float b, float c, float d) {
  union { short4v s; unsigned int u[2]; } z;
  z.u[0] = cvtpk(a, b);
  z.u[1] = cvtpk(c, d);
  return z.s;
}

__device__ __forceinline__ short8v pack8(const float4& fa, const float4& fb) {
  short8v v;
  v[0] = (short)f2bf(fa.x); v[1] = (short)f2bf(fa.y);
  v[2] = (short)f2bf(fa.z); v[3] = (short)f2bf(fa.w);
  v[4] = (short)f2bf(fb.x); v[5] = (short)f2bf(fb.y);
  v[6] = (short)f2bf(fb.z); v[7] = (short)f2bf(fb.w);
  return v;
}

// ---------------- weight fp32->bf16 ----------------
__global__ __launch_bounds__(256) void cvt_w_kernel(const float* __restrict__ w_in,
                                                    const float* __restrict__ w_out,
                                                    short* __restrict__ Wb) {
  int idx = blockIdx.x * 256 + threadIdx.x;  // 393216 total
  float v = (idx < 327680) ? w_in[idx] : w_out[idx - 327680];
  Wb[idx] = (short)f2bf(v);
}

// ---------------- mega1: vproj + mean_h + mean_w (interleaved) ----------------
// blk even -> vproj[blk>>1] (768); blk odd -> id=blk>>1: id<384 mean_h(2 rows),
// else mean_w(2 rows). LDS overlaid: means reuse vproj's buf.
__global__ __launch_bounds__(512, 4) void mega1_kernel(
    const float* __restrict__ A, const short* __restrict__ Wb,
    const float* __restrict__ bias, short* __restrict__ vvT,
    const float* __restrict__ key_row, const float* __restrict__ key_col,
    float* __restrict__ krm, float* __restrict__ kcm) {
  __shared__ float buf[2][16 * 260];   // 33.3 KB (vproj stage / means partials)
  __shared__ short Ts[8][32 * 36];     // 18.4 KB
  int blk = blockIdx.x;
  int t = threadIdx.x;

  if ((blk & 1) == 0) {
    // ---------------- vproj branch (id 0..767), r16 body ----------------
    int vb_id = blk >> 1;
    int wave = t >> 6, lane = t & 63, r = lane & 15, g = lane >> 4;
    int m0g = vb_id * 96;
    int b_ = vb_id / 96;
    int hw00 = (vb_id - b_ * 96) * 96;
    int chbase = wave * 32;

    short8v bf[8][2];
    {
      const short* wbase = Wb + (size_t)(chbase + r) * 256;
#pragma unroll
      for (int ks = 0; ks < 8; ++ks)
#pragma unroll
        for (int nf = 0; nf < 2; ++nf)
          bf[ks][nf] = *(const short8v*)(wbase + nf * 16 * 256 + ks * 32 + g * 8);
    }
#pragma unroll
    for (int ks = 0; ks < 8; ++ks)
#pragma unroll
      for (int nf = 0; nf < 2; ++nf)
        asm volatile("" : "+a"(bf[ks][nf]));
    float bias_v[2];
#pragma unroll
    for (int nf = 0; nf < 2; ++nf) bias_v[nf] = bias[chbase + nf * 16 + r];

#pragma unroll
    for (int q = 0; q < 2; ++q) {
#pragma unroll
      for (int i = 0; i < 2; ++i) {
        int row = wave * 2 + i;
        const float* gp = A + ((size_t)m0g + q * 16 + row) * 256 + lane * 4;
        GLL16(gp, &buf[q][row * 260]);
      }
    }

    int chg = chbase + (lane & 31);
    int half = lane >> 5;
    short* vbase = vvT + (size_t)(b_ * 8 + (chg >> 5)) * 294912 +
                   (size_t)(chg & 31) * 9216 + hw00;
    const short* tsr = &Ts[wave][(lane & 31) * 36];

#pragma unroll
    for (int tt = 0; tt < 6; ++tt) {
      if (tt == 5)                  asm volatile("s_waitcnt vmcnt(0)" ::: "memory");
      else if (tt == 2 || tt == 4)  asm volatile("s_waitcnt vmcnt(4)" ::: "memory");
      else                          asm volatile("s_waitcnt vmcnt(2)" ::: "memory");
      __builtin_amdgcn_s_barrier();

      f32x4 acc[2] = {};
      const float* bp_ = &buf[tt & 1][0];
#pragma unroll
      for (int ks = 0; ks < 8; ++ks) {
        const float* p = bp_ + r * 260 + ks * 32 + g * 8;
        f32x4 lo = *(const f32x4*)p;
        f32x4 hi = *(const f32x4*)(p + 4);
        short8v af = pack8cvt(lo, hi);
        acc[0] = __builtin_amdgcn_mfma_f32_16x16x32_bf16(af, bf[ks][0], acc[0], 0, 0, 0);
        acc[1] = __builtin_amdgcn_mfma_f32_16x16x32_bf16(af, bf[ks][1], acc[1], 0, 0, 0);
      }

#pragma unroll
      for (int nf = 0; nf < 2; ++nf) {
        float bv = bias_v[nf];
        *(short4v*)&Ts[wave][(nf * 16 + r) * 36 + (tt & 1) * 16 + g * 4] =
            pack4cvt(acc[nf][0] + bv, acc[nf][1] + bv, acc[nf][2] + bv, acc[nf][3] + bv);
      }
      asm volatile("" ::: "memory");

      if (tt & 1) {
        short* gdst = vbase + (tt - 1) * 16 + half * 16;
        const short* src = tsr + half * 16;
        *(short8v*)gdst = *(const short8v*)src;
        *(short8v*)(gdst + 8) = *(const short8v*)(src + 8);
        asm volatile("" ::: "memory");
      }

      __builtin_amdgcn_s_barrier();
      if (tt + 2 < 6) {
#pragma unroll
        for (int i = 0; i < 2; ++i) {
          int row = wave * 2 + i;
          const float* gp = A + ((size_t)m0g + (tt + 2) * 16 + row) * 256 + lane * 4;
          GLL16(gp, &buf[tt & 1][row * 260]);
        }
      }
    }
  } else {
    // ---------------- means branch (id 0..767): 2 output rows per block ----
    int id = blk >> 1;
    int sub = t >> 8, u = t & 255;
    int e4 = u & 63, q4 = u >> 6;
    float4* part4 = (float4*)&buf[0][0];  // 512 float4 = 8KB overlay
    if (id < 384) {
      int bw = id * 2 + sub;  // b*96+w
      int b = bw / 96, w = bw - b * 96;
      const float4* p = (const float4*)(key_row + ((size_t)b * 9216 + w) * 256) +
                        e4 + (size_t)q4 * 24 * 6144;
      float4 s = {0.f, 0.f, 0.f, 0.f};
#pragma unroll
      for (int i = 0; i < 24; ++i) {
        float4 v = p[(size_t)i * 6144];
        s.x += v.x; s.y += v.y; s.z += v.z; s.w += v.w;
      }
      part4[sub * 256 + u] = s;
      __syncthreads();
      if (u < 64) {
        float4 a = part4[sub * 256 + u], c = part4[sub * 256 + u + 64];
        float4 d = part4[sub * 256 + u + 128], e = part4[sub * 256 + u + 192];
        float4 o;
        o.x = (a.x + c.x + d.x + e.x) * (1.f / 96.f);
        o.y = (a.y + c.y + d.y + e.y) * (1.f / 96.f);
        o.z = (a.z + c.z + d.z + e.z) * (1.f / 96.f);
        o.w = (a.w + c.w + d.w + e.w) * (1.f / 96.f);
        ((float4*)krm)[(size_t)bw * 64 + u] = o;
      }
    } else {
      int bh = (id - 384) * 2 + sub;  // b*96+h
      const float4* p = (const float4*)(key_col + (size_t)bh * 24576) + e4 +
                        (size_t)q4 * 24 * 64;
      float4 s = {0.f, 0.f, 0.f, 0.f};
#pragma unroll
      for (int i = 0; i < 24; ++i) {
        float4 v = p[(size_t)i * 64];
        s.x += v.x; s.y += v.y; s.z += v.z; s.w += v.w;
      }
      part4[sub * 256 + u] = s;
      __syncthreads();
      if (u < 64) {
        float4 a = part4[sub * 256 + u], c = part4[sub * 256 + u + 64];
        float4 d = part4[sub * 256 + u + 128], e = part4[sub * 256 + u + 192];
        float4 o;
        o.x = (a.x + c.x + d.x + e.x) * (1.f / 96.f);
        o.y = (a.y + c.y + d.y + e.y) * (1.f / 96.f);
        o.z = (a.z + c.z + d.z + e.z) * (1.f / 96.f);
        o.w = (a.w + c.w + d.w + e.w) * (1.f / 96.f);
        ((float4*)kcm)[(size_t)bh * 64 + u] = o;
      }
    }
  }
}

// ---------------- gemm512: kproj + qproj in one launch ----------------
// 100 blocks x 512 thr; each block = 64 rows as two 256-thr sub-tiles.
// id<12: krm->krb; id<24: kcm->kcb; id<62: qr->qrb; else qc->qcb.
__global__ __launch_bounds__(512) void gemm512(
    const float* __restrict__ krm, const float* __restrict__ kcm,
    const float* __restrict__ qrow, const float* __restrict__ qcol,
    const short* __restrict__ Wb, const float* __restrict__ Bv,
    short* __restrict__ krb, short* __restrict__ kcb,
    short* __restrict__ qrb, short* __restrict__ qcb) {
  __shared__ short As[2][32 * 264];
  int id = blockIdx.x;
  const float* A; short* Cb; const short* Wp; const float* bp; int M, m064;
  float scale;
  if (id < 12)      { A = krm;  Cb = krb; Wp = Wb + 131072; bp = Bv + 512; M = 768;  m064 = id * 64;        scale = 1.f; }
  else if (id < 24) { A = kcm;  Cb = kcb; Wp = Wb + 196608; bp = Bv + 768; M = 768;  m064 = (id - 12) * 64; scale = 1.f; }
  else if (id < 62) { A = qrow; Cb = qrb; Wp = Wb;          bp = Bv;       M = 2400; m064 = (id - 24) * 64; scale = SCALE_Q; }
  else              { A = qcol; Cb = qcb; Wp = Wb + 65536;  bp = Bv + 256; M = 2400; m064 = (id - 62) * 64; scale = SCALE_Q; }

  int t = threadIdx.x, sub = t >> 8, u = t & 255;
  int wave = u >> 6, lane = u & 63, r = lane & 15, g = lane >> 4;
  int m0 = m064 + sub * 32;

  {
    int row = u >> 3, c0 = (u & 7) * 32;
    int mrow = m0 + row; if (mrow >= M) mrow = M - 1;
    const float* ap = A + (size_t)mrow * 256 + c0;
    float4 ld[8];
#pragma unroll
    for (int j = 0; j < 8; ++j) ld[j] = *(const float4*)(ap + j * 4);
    short* dst = &As[sub][row * 264 + c0];
#pragma unroll
    for (int j = 0; j < 4; ++j)
      *(short8v*)(dst + j * 8) = pack8(ld[2 * j], ld[2 * j + 1]);
  }
  __syncthreads();

  f32x4 acc[2][4] = {};
  const short* wbase = Wp + (size_t)(wave * 64 + r) * 256;
#pragma unroll
  for (int ks = 0; ks < 8; ++ks) {
    short8v af0 = *(const short8v*)&As[sub][r * 264 + ks * 32 + g * 8];
    short8v af1 = *(const short8v*)&As[sub][(16 + r) * 264 + ks * 32 + g * 8];
    short8v bf[4];
#pragma unroll
    for (int nf = 0; nf < 4; ++nf)
      bf[nf] = *(const short8v*)(wbase + nf * 16 * 256 + ks * 32 + g * 8);
#pragma unroll
    for (int nf = 0; nf < 4; ++nf) {
      acc[0][nf] = __builtin_amdgcn_mfma_f32_16x16x32_bf16(af0, bf[nf], acc[0][nf], 0, 0, 0);
      acc[1][nf] = __builtin_amdgcn_mfma_f32_16x16x32_bf16(af1, bf[nf], acc[1][nf], 0, 0, 0);
    }
  }

#pragma unroll
  for (int mf = 0; mf < 2; ++mf)
#pragma unroll
    for (int nf = 0; nf < 4; ++nf) {
      int nn = wave * 64 + nf * 16 + r;
      float bval = bp[nn];
#pragma unroll
      for (int i = 0; i < 4; ++i) {
        int m = m0 + mf * 16 + g * 4 + i;
        if (m >= M) continue;
        Cb[(size_t)m * 256 + nn] = (short)f2bf((acc[mf][nf][i] + bval) * scale);
      }
    }
}

// ---------------- out-projection: (part0+part1) @ Wout^T + Bout ----------------
__global__ __launch_bounds__(512) void gemm512_out(
    const float* __restrict__ A0, const float* __restrict__ Aadd,
    const short* __restrict__ Wp, const float* __restrict__ bp,
    float* __restrict__ Cf) {
  __shared__ short As[2][32 * 264];
  const int M = 2400;
  int t = threadIdx.x, sub = t >> 8, u = t & 255;
  int wave = u >> 6, lane = u & 63, r = lane & 15, g = lane >> 4;
  int m0 = blockIdx.x * 64 + sub * 32;

  {
    int row = u >> 3, c0 = (u & 7) * 32;
    int mrow = m0 + row; if (mrow >= M) mrow = M - 1;
    size_t off = (size_t)mrow * 256 + c0;
    const float* ap = A0 + off;
    const float* aq = Aadd + off;
    float4 ld[8];
#pragma unroll
    for (int j = 0; j < 8; ++j) {
      float4 x = *(const float4*)(ap + j * 4);
      float4 e = *(const float4*)(aq + j * 4);
      x.x += e.x; x.y += e.y; x.z += e.z; x.w += e.w;
      ld[j] = x;
    }
    short* dst = &As[sub][row * 264 + c0];
#pragma unroll
    for (int j = 0; j < 4; ++j)
      *(short8v*)(dst + j * 8) = pack8(ld[2 * j], ld[2 * j + 1]);
  }
  __syncthreads();

  f32x4 acc[2][4] = {};
  const short* wbase = Wp + (size_t)(wave * 64 + r) * 256;
#pragma unroll
  for (int ks = 0; ks < 8; ++ks) {
    short8v af0 = *(const short8v*)&As[sub][r * 264 + ks * 32 + g * 8];
    short8v af1 = *(const short8v*)&As[sub][(16 + r) * 264 + ks * 32 + g * 8];
    short8v bf[4];
#pragma unroll
    for (int nf = 0; nf < 4; ++nf)
      bf[nf] = *(const short8v*)(wbase + nf * 16 * 256 + ks * 32 + g * 8);
#pragma unroll
    for (int nf = 0; nf < 4; ++nf) {
      acc[0][nf] = __builtin_amdgcn_mfma_f32_16x16x32_bf16(af0, bf[nf], acc[0][nf], 0, 0, 0);
      acc[1][nf] = __builtin_amdgcn_mfma_f32_16x16x32_bf16(af1, bf[nf], acc[1][nf], 0, 0, 0);
    }
  }

#pragma unroll
  for (int mf = 0; mf < 2; ++mf)
#pragma unroll
    for (int nf = 0; nf < 4; ++nf) {
      int nn = wave * 64 + nf * 16 + r;
      float bval = bp[nn];
#pragma unroll
      for (int i = 0; i < 4; ++i) {
        int m = m0 + mf * 16 + g * 4 + i;
        if (m >= M) continue;
        int bb = m / 300, ll = m - bb * 300;
        Cf[((size_t)ll * 8 + bb) * 256 + nn] = acc[mf][nf][i] + bval;
      }
    }
}

// ---------------- scores + softmax: MFMA + in-register softmax ----------------
__global__ __launch_bounds__(64) void scores_softmax_v2(
    const short* __restrict__ qrb, const short* __restrict__ qcb,
    const short* __restrict__ krb, const short* __restrict__ kcb,
    short* __restrict__ wrowB, float* __restrict__ wcolT) {
  int lchunk = blockIdx.x, bn = blockIdx.y, kind = blockIdx.z;
  int b = bn >> 3, n = bn & 7;
  int lane = threadIdx.x;
  int r = lane & 15, g = lane >> 4;
  const short* qb = kind ? qcb : qrb;
  const short* kb = kind ? kcb : krb;
  int l0 = lchunk * 80;

  short8v a[5], bfr[6];
#pragma unroll
  for (int lf = 0; lf < 5; ++lf) {
    int l = l0 + lf * 16 + r;
    if (l > 299) l = 299;
    a[lf] = *(const short8v*)(qb + ((size_t)b * 300 + l) * 256 + n * 32 + g * 8);
  }
#pragma unroll
  for (int f = 0; f < 6; ++f)
    bfr[f] = *(const short8v*)(kb + ((size_t)b * 96 + f * 16 + r) * 256 + n * 32 + g * 8);

  f32x4 c[5][6];
#pragma unroll
  for (int lf = 0; lf < 5; ++lf)
#pragma unroll
    for (int f = 0; f < 6; ++f) {
      f32x4 z = {};
      c[lf][f] = __builtin_amdgcn_mfma_f32_16x16x32_bf16(a[lf], bfr[f], z, 0, 0, 0);
    }

#pragma unroll
  for (int lf = 0; lf < 5; ++lf)
#pragma unroll
    for (int i = 0; i < 4; ++i) {
      float m = c[lf][0][i];
#pragma unroll
      for (int f = 1; f < 6; ++f) m = fmaxf(m, c[lf][f][i]);
#pragma unroll
      for (int mask = 1; mask <= 8; mask <<= 1) m = fmaxf(m, __shfl_xor(m, mask, 64));
      float e[6], s = 0.f;
#pragma unroll
      for (int f = 0; f < 6; ++f) { e[f] = __expf(c[lf][f][i] - m); s += e[f]; }
#pragma unroll
      for (int mask = 1; mask <= 8; mask <<= 1) s += __shfl_xor(s, mask, 64);
      float inv = 1.f / s;
#pragma unroll
      for (int f = 0; f < 6; ++f) c[lf][f][i] = e[f] * inv;
    }

  if (kind == 0) {
#pragma unroll
    for (int lf = 0; lf < 5; ++lf)
#pragma unroll
      for (int i = 0; i < 4; ++i) {
        int l = l0 + lf * 16 + g * 4 + i;
        bool ok = (l < 300);
#pragma unroll
        for (int f = 0; f < 6; ++f) {
          float wv = ok ? c[lf][f][i] : 0.f;
          wrowB[((size_t)bn * 320 + l) * 96 + f * 16 + r] = (short)f2bf(wv);
        }
      }
  } else {
#pragma unroll
    for (int lf = 0; lf < 5; ++lf)
#pragma unroll
      for (int f = 0; f < 6; ++f) {
        int l = l0 + lf * 16 + g * 4;
        f32x4 wv = c[lf][f];
#pragma unroll
        for (int i = 0; i < 4; ++i) if (l + i >= 300) wv[i] = 0.f;
        *(f32x4*)(wcolT + ((size_t)bn * 96 + f * 16 + r) * 320 + l) = wv;
      }
  }
}

// ---------------- fused bilinear attention (r16: h split x2) ----------
__global__ __launch_bounds__(512, 2) void attn_kernel(
    const short* __restrict__ wrowB, const float* __restrict__ wcolT,
    const short* __restrict__ vvT, float* __restrict__ part0,
    float* __restrict__ part1) {
  __shared__ f32x4 cmb[3][2][4][64];
  int i = blockIdx.x;
  int xcd = i & 7, j = i >> 3;          // j 0..79
  int grp = j / 10, rem = j - grp * 10;
  int bn = grp * 8 + xcd;               // all 10 blocks of a bn -> same XCD
  int lh = rem >> 1, hh2 = rem & 1;
  int b = bn >> 3, n = bn & 7;
  int t = threadIdx.x, wave = t >> 6, lane = t & 63;
  int df = wave & 1, hq = wave >> 1;    // hq 0..3, 12 h each
  int lbase = lh * 64;
  int r = lane & 15, g = lane >> 4;
  int hbase = hh2 * 48 + hq * 12;

  short8v a[4][3];
  const short* wr = wrowB + (size_t)bn * 320 * 96;
#pragma unroll
  for (int lf = 0; lf < 4; ++lf)
#pragma unroll
    for (int ks = 0; ks < 3; ++ks)
      a[lf][ks] = *(const short8v*)(wr + (lbase + lf * 16 + r) * 96 + ks * 32 + g * 8);

  const short* vb = vvT + (size_t)bn * 294912 + (size_t)(df * 16 + r) * 9216 + hbase * 96;
  const float* wcb = wcolT + ((size_t)bn * 96 + hbase) * 320 + lbase + g * 4;

  f32x4 acc[4] = {};
  short8v b0[3], b1[3];
  f32x4 w0[4], w1[4];
#pragma unroll
  for (int ks = 0; ks < 3; ++ks) b0[ks] = *(const short8v*)(vb + ks * 32 + g * 8);
#pragma unroll
  for (int lf = 0; lf < 4; ++lf) w0[lf] = *(const f32x4*)(wcb + lf * 16);

#pragma unroll
  for (int h2 = 0; h2 < 6; ++h2) {
    int h = h2 * 2;
#pragma unroll
    for (int ks = 0; ks < 3; ++ks) b1[ks] = *(const short8v*)(vb + (h + 1) * 96 + ks * 32 + g * 8);
#pragma unroll
    for (int lf = 0; lf < 4; ++lf) w1[lf] = *(const f32x4*)(wcb + (h + 1) * 320 + lf * 16);
    {
      f32x4 R[4] = {};
#pragma unroll
      for (int ks = 0; ks < 3; ++ks)
#pragma unroll
        for (int lf = 0; lf < 4; ++lf)
          R[lf] = __builtin_amdgcn_mfma_f32_16x16x32_bf16(a[lf][ks], b0[ks], R[lf], 0, 0, 0);
#pragma unroll
      for (int lf = 0; lf < 4; ++lf) acc[lf] += w0[lf] * R[lf];
    }
    if (h2 < 5) {
#pragma unroll
      for (int ks = 0; ks < 3; ++ks) b0[ks] = *(const short8v*)(vb + (h + 2) * 96 + ks * 32 + g * 8);
#pragma unroll
      for (int lf = 0; lf < 4; ++lf) w0[lf] = *(const f32x4*)(wcb + (h + 2) * 320 + lf * 16);
    }
    {
      f32x4 R[4] = {};
#pragma unroll
      for (int ks = 0; ks < 3; ++ks)
#pragma unroll
        for (int lf = 0; lf < 4; ++lf)
          R[lf] = __builtin_amdgcn_mfma_f32_16x16x32_bf16(a[lf][ks], b1[ks], R[lf], 0, 0, 0);
#pragma unroll
      for (int lf = 0; lf < 4; ++lf) acc[lf] += w1[lf] * R[lf];
    }
  }

  if (hq > 0) {
#pragma unroll
    for (int lf = 0; lf < 4; ++lf) cmb[hq - 1][df][lf][lane] = acc[lf];
  }
  __syncthreads();
  if (hq == 0) {
    float* po = hh2 ? part1 : part0;
#pragma unroll
    for (int lf = 0; lf < 4; ++lf) {
      f32x4 o = acc[lf];
#pragma unroll
      for (int q = 0; q < 3; ++q) o += cmb[q][df][lf][lane];
#pragma unroll
      for (int i2 = 0; i2 < 4; ++i2) {
        int l = lbase + lf * 16 + g * 4 + i2;
        if (l < 300)
          po[((size_t)b * 300 + l) * 256 + n * 32 + df * 16 + r] = o[i2];
      }
    }
  }
}

// ---------------- launch ----------------
extern "C" void kernel_launch(void* const* d_in, const int* in_sizes, int n_in,
                              void* d_out, int out_size, void* d_ws, size_t ws_size,
                              hipStream_t stream) {
  const float* query_row = (const float*)d_in[0];
  const float* query_col = (const float*)d_in[1];
  const float* key_row   = (const float*)d_in[2];
  const float* key_col   = (const float*)d_in[3];
  const float* value     = (const float*)d_in[4];
  const float* W         = (const float*)d_in[5];  // (1280,256)
  const float* Bv        = (const float*)d_in[6];  // (1280,)
  const float* Wout      = (const float*)d_in[7];  // (256,256)
  const float* Bout      = (const float*)d_in[8];  // (256,)

  float* ws = (float*)d_ws;
  float* krm   = ws;                        // 196608 f
  float* kcm   = krm + 196608;              // 196608 f
  float* part0 = kcm + 196608;              // 614400 f
  float* part1 = part0 + 614400;            // 614400 f
  float* wcolT = part1 + 614400;            // 1966080 f
  short* qrb   = (short*)(wcolT + 1966080); // 614400 s
  short* qcb   = qrb + 614400;              // 614400 s
  short* krb   = qcb + 614400;              // 196608 s
  short* kcb   = krb + 196608;              // 196608 s
  short* wrowB = kcb + 196608;              // 1966080 s
  short* vvT   = wrowB + 1966080;           // 18874368 s
  short* Wb    = vvT + 18874368;            // 393216 s

  cvt_w_kernel<<<1536, 256, 0, stream>>>(W, Wout, Wb);
  mega1_kernel<<<1536, 512, 0, stream>>>(value, Wb + 262144, Bv + 1024, vvT,
                                         key_row, key_col, krm, kcm);
  gemm512<<<100, 512, 0, stream>>>(krm, kcm, query_row, query_col, Wb, Bv,
                                   krb, kcb, qrb, qcb);
  scores_softmax_v2<<<dim3(4, 64, 2), 64, 0, stream>>>(qrb, qcb, krb, kcb, wrowB, wcolT);
  attn_kernel<<<640, 512, 0, stream>>>(wrowB, wcolT, vvT, part0, part1);
  gemm512_out<<<38, 512, 0, stream>>>(part0, part1, Wb + 327680, Bout, (float*)d_out);
}